// Round 3
// 102.006 us; speedup vs baseline: 1.0060x; 1.0060x over previous
//
#include <hip/hip_runtime.h>
#include <math.h>

// Canny front-end, LDS-free register-streaming version.
// Each thread owns one float4 column (4 px wide) and slides down an R-row
// strip, holding rolling register windows: 5 rows of h-blurred values
// (6 floats: cols 4j-1..4j+4) and 3 rows of fully-blurred values.
// Horizontal neighbors come from overlapping global float4 loads (L1/L2
// absorb the 3x overlap). Zero LDS, zero barriers -> no stage serialization.
//
// R=16 (was 8): vertical halo amplification drops 1.75x -> 1.375x, cutting
// both redundant reads and redundant h/v-blur VALU work ~20%/15%. Grid is
// 512 blocks = 2 blocks/CU, 8 waves/CU; the fully-unrolled 22-row stream
// provides the ILP to cover HBM/LLC latency at that occupancy.
//
// Nontemporal output store uses a clang native vector type --
// __builtin_nontemporal_store rejects HIP_vector_type<float,4>.
//
// Semantics preserved per reference: h-conv zero-pads columns of img,
// v-conv zero-pads rows of t, sobel zero-pads rows AND columns of blurred
// (blurred col -1 / col 1024 are zeroed explicitly at the edge threads).

#define H_IMG 1024
#define W_IMG 1024
#define W4 (W_IMG / 4)   // 256 float4 columns = one block spans full width
#define R 16             // output rows per strip; window = R+6 = 22 rows

typedef float vf4 __attribute__((ext_vector_type(4)));

__global__ __launch_bounds__(256) void canny_stream(
    const float* __restrict__ img,
    const float* __restrict__ gauss,   // 5 taps [g0,g1,g2,g1,g0]
    float* __restrict__ out)
{
    const int j  = threadIdx.x;            // float4 column index 0..255
    const int y0 = blockIdx.x * R;         // first output row of this strip
    const int b  = blockIdx.y;             // image index

    const float g0 = gauss[0], g1 = gauss[1], g2 = gauss[2];
    const float* __restrict__ imgb = img + (size_t)b * (H_IMG * W_IMG);
    float* __restrict__ outb       = out + (size_t)b * (H_IMG * W_IMG);
    const int xc = 4 * j;

    float hb[5][6];   // h-blurred rows, cols xc-1..xc+4 ; row (y0-3+it) at slot it%5
    float bl[3][6];   // blurred rows                    ; row (y0-5+it) at slot (it-4)%3

    #pragma unroll
    for (int it = 0; it < R + 6; ++it) {
        // ---- ingest raw row ry, h-blur into window ----
        const int ry = y0 - 3 + it;
        float* h = hb[it % 5];
        if (ry >= 0 && ry < H_IMG) {
            const float* p = imgb + ry * W_IMG + xc;
            float4 A = make_float4(0.f, 0.f, 0.f, 0.f);
            float4 C = make_float4(0.f, 0.f, 0.f, 0.f);
            if (j > 0)      A = *(const float4*)(p - 4);   // cols xc-4..xc-1
            float4 B = *(const float4*)(p);                // cols xc  ..xc+3
            if (j < W4 - 1) C = *(const float4*)(p + 4);   // cols xc+4..xc+7
            h[0] = g0 * (A.y + B.y) + g1 * (A.z + B.x) + g2 * A.w;  // col xc-1
            h[1] = g0 * (A.z + B.z) + g1 * (A.w + B.y) + g2 * B.x;  // col xc
            h[2] = g0 * (A.w + B.w) + g1 * (B.x + B.z) + g2 * B.y;  // col xc+1
            h[3] = g0 * (B.x + C.x) + g1 * (B.y + B.w) + g2 * B.z;  // col xc+2
            h[4] = g0 * (B.y + C.y) + g1 * (B.z + C.x) + g2 * B.w;  // col xc+3
            h[5] = g0 * (B.z + C.z) + g1 * (B.w + C.y) + g2 * C.x;  // col xc+4
        } else {
            #pragma unroll
            for (int k = 0; k < 6; ++k) h[k] = 0.0f;   // v-conv zero-pad of t rows
        }

        // ---- v-blur: once 5 hb rows live, produce blurred row by = ry-2 ----
        if (it >= 4) {
            const int by = ry - 2;
            float* o = bl[(it - 4) % 3];
            if (by >= 0 && by < H_IMG) {
                const float* h0 = hb[(it - 4) % 5];   // t(by-2)
                const float* h1 = hb[(it - 3) % 5];   // t(by-1)
                const float* h2 = hb[(it - 2) % 5];   // t(by)
                const float* h3 = hb[(it - 1) % 5];   // t(by+1)
                const float* h4 = hb[(it    ) % 5];   // t(by+2)
                #pragma unroll
                for (int k = 0; k < 6; ++k)
                    o[k] = g0 * (h0[k] + h4[k]) + g1 * (h1[k] + h3[k]) + g2 * h2[k];
                // sobel's zero-pad of blurred COLUMNS:
                if (j == 0)      o[0] = 0.0f;   // blurred col -1
                if (j == W4 - 1) o[5] = 0.0f;   // blurred col 1024
            } else {
                #pragma unroll
                for (int k = 0; k < 6; ++k) o[k] = 0.0f;  // sobel zero-pad of rows
            }
        }

        // ---- sobel + mag + threshold on output row oy = ry-3 ----
        if (it >= 6) {
            const int oy = ry - 3;                       // in [y0, y0+R-1]
            const float* T  = bl[(it - 6) % 3];          // blurred(oy-1)
            const float* M  = bl[(it - 5) % 3];          // blurred(oy)
            const float* Bo = bl[(it - 4) % 3];          // blurred(oy+1)
            vf4 o4;
            #pragma unroll
            for (int k = 0; k < 4; ++k) {                // out col xc+k -> idx k..k+2
                float gx = (T[k] - T[k + 2]) + 2.0f * (M[k] - M[k + 2]) + (Bo[k] - Bo[k + 2]);
                float gy = (T[k] + 2.0f * T[k + 1] + T[k + 2])
                         - (Bo[k] + 2.0f * Bo[k + 1] + Bo[k + 2]);
                float mag = sqrtf(gx * gx + gy * gy);
                o4[k] = (mag < 2.0f) ? 0.0f : mag;
            }
            // Output is never re-read: nontemporal store keeps L2/LLC lines
            // free for halo-row reuse.
            __builtin_nontemporal_store(o4, (vf4*)(outb + oy * W_IMG + xc));
        }
    }
}

extern "C" void kernel_launch(void* const* d_in, const int* in_sizes, int n_in,
                              void* d_out, int out_size, void* d_ws, size_t ws_size,
                              hipStream_t stream) {
    const float* img   = (const float*)d_in[0];
    const float* gauss = (const float*)d_in[1];
    float* out = (float*)d_out;
    const int N = in_sizes[0] / (H_IMG * W_IMG);   // = 8

    dim3 grid(H_IMG / R, N);                       // (64, 8) = 512 blocks
    canny_stream<<<grid, 256, 0, stream>>>(img, gauss, out);
}

// Round 4
// 101.788 us; speedup vs baseline: 1.0081x; 1.0021x over previous
//
#include <hip/hip_runtime.h>
#include <math.h>

// Canny front-end, LDS-free register-streaming version.
// Each thread owns one float4 column (4 px wide) and slides down an R-row
// strip, holding rolling register windows: 5 rows of h-blurred values
// (6 floats: cols 4j-1..4j+4) and 3 rows of fully-blurred values.
//
// R=8: 1024 blocks = 4 blocks/CU = 4 waves/SIMD. R=16 (prev round) profiled
// at 72us, latency-bound (VALUBusy 17%, occ 21.7%, HBM 10%): 2 waves/SIMD
// with load-use distance ~0 cannot hide 200-900cy load latency. Halo cost
// (1.75x reads) is irrelevant at 10% of HBM peak -> buy TLP back.
//
// Depth-2 software prefetch: row it+2's three float4 loads are issued while
// computing row it, giving each wave ~2 iterations (~150-300cy) of load-use
// distance; x4 waves/SIMD covers HBM-miss latency. OOR rows prefetch zeros
// (h-blur of zeros == zeros == the v-conv zero-pad semantics), removing the
// bounds branch from the compute path.
//
// Nontemporal output store (never re-read) keeps L2/LLC lines free for
// halo-row reuse. Uses a clang native vector type; the builtin rejects
// HIP_vector_type<float,4>.
//
// Semantics preserved per reference: h-conv zero-pads columns of img,
// v-conv zero-pads rows of t, sobel zero-pads rows AND columns of blurred
// (blurred col -1 / col 1024 are zeroed explicitly at the edge threads).

#define H_IMG 1024
#define W_IMG 1024
#define W4 (W_IMG / 4)   // 256 float4 columns = one block spans full width
#define R 8              // output rows per strip; window = R+6 = 14 rows
#define NIT (R + 6)

typedef float vf4 __attribute__((ext_vector_type(4)));

__global__ __launch_bounds__(256, 4) void canny_stream(
    const float* __restrict__ img,
    const float* __restrict__ gauss,   // 5 taps [g0,g1,g2,g1,g0]
    float* __restrict__ out)
{
    const int j  = threadIdx.x;            // float4 column index 0..255
    const int y0 = blockIdx.x * R;         // first output row of this strip
    const int b  = blockIdx.y;             // image index

    const float g0 = gauss[0], g1 = gauss[1], g2 = gauss[2];
    const float* __restrict__ imgb = img + (size_t)b * (H_IMG * W_IMG);
    float* __restrict__ outb       = out + (size_t)b * (H_IMG * W_IMG);
    const int xc = 4 * j;

    float hb[5][6];   // h-blurred rows, cols xc-1..xc+4 ; row (y0-3+it) at slot it%5
    float bl[3][6];   // blurred rows                    ; row (y0-5+it) at slot (it-4)%3

    // 2-slot prefetch pipeline for the raw-row loads (slot = it&1; after the
    // full unroll every index is compile-time constant -> stays in VGPRs).
    float4 pA[2], pB[2], pC[2];

    auto loadrow = [&](int it, int slot) {
        const int ry = y0 - 3 + it;
        float4 A = make_float4(0.f, 0.f, 0.f, 0.f);
        float4 B = make_float4(0.f, 0.f, 0.f, 0.f);
        float4 C = make_float4(0.f, 0.f, 0.f, 0.f);
        if (ry >= 0 && ry < H_IMG) {       // wave-uniform branch
            const float* p = imgb + ry * W_IMG + xc;
            if (j > 0)      A = *(const float4*)(p - 4);   // cols xc-4..xc-1
            B = *(const float4*)(p);                       // cols xc  ..xc+3
            if (j < W4 - 1) C = *(const float4*)(p + 4);   // cols xc+4..xc+7
        }
        pA[slot] = A; pB[slot] = B; pC[slot] = C;
    };

    loadrow(0, 0);
    loadrow(1, 1);

    #pragma unroll
    for (int it = 0; it < NIT; ++it) {
        const int ry = y0 - 3 + it;

        // consume this row's prefetched loads, then immediately issue it+2's
        const float4 A = pA[it & 1], B = pB[it & 1], C = pC[it & 1];
        if (it + 2 < NIT) loadrow(it + 2, it & 1);

        // ---- h-blur raw row ry into the rolling window ----
        // (A=B=C=0 for out-of-range rows -> h[] = 0 == v-conv zero-pad)
        float* h = hb[it % 5];
        h[0] = g0 * (A.y + B.y) + g1 * (A.z + B.x) + g2 * A.w;  // col xc-1
        h[1] = g0 * (A.z + B.z) + g1 * (A.w + B.y) + g2 * B.x;  // col xc
        h[2] = g0 * (A.w + B.w) + g1 * (B.x + B.z) + g2 * B.y;  // col xc+1
        h[3] = g0 * (B.x + C.x) + g1 * (B.y + B.w) + g2 * B.z;  // col xc+2
        h[4] = g0 * (B.y + C.y) + g1 * (B.z + C.x) + g2 * B.w;  // col xc+3
        h[5] = g0 * (B.z + C.z) + g1 * (B.w + C.y) + g2 * C.x;  // col xc+4

        // ---- v-blur: once 5 hb rows live, produce blurred row by = ry-2 ----
        if (it >= 4) {
            const int by = ry - 2;
            float* o = bl[(it - 4) % 3];
            if (by >= 0 && by < H_IMG) {
                const float* h0 = hb[(it - 4) % 5];   // t(by-2)
                const float* h1 = hb[(it - 3) % 5];   // t(by-1)
                const float* h2 = hb[(it - 2) % 5];   // t(by)
                const float* h3 = hb[(it - 1) % 5];   // t(by+1)
                const float* h4 = hb[(it    ) % 5];   // t(by+2)
                #pragma unroll
                for (int k = 0; k < 6; ++k)
                    o[k] = g0 * (h0[k] + h4[k]) + g1 * (h1[k] + h3[k]) + g2 * h2[k];
                // sobel's zero-pad of blurred COLUMNS:
                if (j == 0)      o[0] = 0.0f;   // blurred col -1
                if (j == W4 - 1) o[5] = 0.0f;   // blurred col 1024
            } else {
                #pragma unroll
                for (int k = 0; k < 6; ++k) o[k] = 0.0f;  // sobel zero-pad of rows
            }
        }

        // ---- sobel + mag + threshold on output row oy = ry-3 ----
        if (it >= 6) {
            const int oy = ry - 3;                       // in [y0, y0+R-1]
            const float* T  = bl[(it - 6) % 3];          // blurred(oy-1)
            const float* M  = bl[(it - 5) % 3];          // blurred(oy)
            const float* Bo = bl[(it - 4) % 3];          // blurred(oy+1)
            vf4 o4;
            #pragma unroll
            for (int k = 0; k < 4; ++k) {                // out col xc+k -> idx k..k+2
                float gx = (T[k] - T[k + 2]) + 2.0f * (M[k] - M[k + 2]) + (Bo[k] - Bo[k + 2]);
                float gy = (T[k] + 2.0f * T[k + 1] + T[k + 2])
                         - (Bo[k] + 2.0f * Bo[k + 1] + Bo[k + 2]);
                float mag = sqrtf(gx * gx + gy * gy);
                o4[k] = (mag < 2.0f) ? 0.0f : mag;
            }
            __builtin_nontemporal_store(o4, (vf4*)(outb + oy * W_IMG + xc));
        }
    }
}

extern "C" void kernel_launch(void* const* d_in, const int* in_sizes, int n_in,
                              void* d_out, int out_size, void* d_ws, size_t ws_size,
                              hipStream_t stream) {
    const float* img   = (const float*)d_in[0];
    const float* gauss = (const float*)d_in[1];
    float* out = (float*)d_out;
    const int N = in_sizes[0] / (H_IMG * W_IMG);   // = 8

    dim3 grid(H_IMG / R, N);                       // (128, 8) = 1024 blocks
    canny_stream<<<grid, 256, 0, stream>>>(img, gauss, out);
}